// Round 17
// baseline (146.071 us; speedup 1.0000x reference)
//
#include <hip/hip_runtime.h>
#include <math.h>

#define NB 16
#define NC 512
#define NK 128
#define SP 4096   // 64*64 spatial positions

typedef __attribute__((ext_vector_type(8))) short short8;
typedef __attribute__((ext_vector_type(4))) float f32x4;

__device__ inline unsigned short f2bf(float f) {
    unsigned int u = __builtin_bit_cast(unsigned int, f);
    u += 0x7fffu + ((u >> 16) & 1u);   // RNE
    return (unsigned short)(u >> 16);
}

// LDS act layout ([32 pos][128 i]): byte(pos, iloc) = pos*256 + (G<<4) + (iloc&7)*2,
//   G = (iloc>>3) ^ (pos&7) ^ ((pos>>3)&7)
__device__ __forceinline__ int swzbyte(int pos, int iloc) {
    return pos * 256 + ((((iloc >> 3) ^ (pos & 7) ^ ((pos >> 3) & 7)) & 15) << 4) + (iloc & 7) * 2;
}

// ---------------------------------------------------------------------------
// ws layout (float offsets):
//   [0..2047] SY  [2048..4095] SX1  [4096..6143] SX2
//   [6144..22527]  sbr (2 br * 16 b * 512 c)
//   [22528..55295] wpre0 : wb pre-swizzled to per-wave B-frag order (65536 u16)
//   [55296..88063] wpre1 : wa (col-permuted) same order             (65536 u16)
//
// wpre element order: o = idx16*512 + lane*8 + el, where
//   idx16 = (ch*4 + kk)*8 + t8   (t8 = global 16-k tile 0..7)
//   k = t8*16 + (lane&15);  i = ch*128 + kk*32 + (lane>>4)*8 + el
// For wpre1 the logical column i' maps to wa column 8*(i'&63) + (i'>>6).
// ---------------------------------------------------------------------------

__global__ __launch_bounds__(256) void prep_weights(
    const float* __restrict__ wa, const float* __restrict__ wb,
    unsigned short* __restrict__ w0, unsigned short* __restrict__ w1,
    float* __restrict__ zbase) {
    int o = blockIdx.x * 256 + threadIdx.x;   // 0..65535
    if (o < 6144) zbase[o] = 0.f;             // zero SY/SX1/SX2 (replaces memset)
    int idx16 = o >> 9;
    int lane = (o >> 3) & 63;
    int el = o & 7;
    int t8 = idx16 & 7;
    int kk = (idx16 >> 3) & 3;
    int ch = idx16 >> 5;
    int k = t8 * 16 + (lane & 15);
    int i = ch * 128 + kk * 32 + (lane >> 4) * 8 + el;
    w0[o] = f2bf(wb[k * 512 + i]);
    int col1 = 8 * (i & 63) + (i >> 6);
    w1[o] = f2bf(wa[k * 512 + col1]);
}

// ---------------------------------------------------------------------------
// Conv+mean body, verified fragment math; 32-pos tiles for small accumulators.
// Block (g 0..127, b), 256 thr = 4 waves; wave kq owns k-range kq*32..+32
// (2 nt-tiles), all 32 pos (2 pt-tiles). acc[2][2] = 16 regs/wave.
// VIEW 0: pos = s-in-tile (s = g*32+pos); i = c = ch*128+iloc
// VIEW 1: pos = h-half (j = g>>1, hh = g&1, h = hh*32+pos);
//         iloc (qh=iloc>>6, w=iloc&63) -> x[b, 64*(2ch+qh)+(g>>1), w, h]
// VIEW 2: pos = cl4*8+jh (c = 8*(g>>1)+4*(g&1)+cl4); i'=128ch+64qh+h ->
//         x[b, c, 8*(2ch+qh)+jh, h]
// ---------------------------------------------------------------------------
template <int VIEW>
__device__ __forceinline__ void conv_body(
    const float* __restrict__ x, const unsigned short* __restrict__ wpre,
    const float* __restrict__ bias, float* __restrict__ Ssum,
    unsigned short* actS, float* red) {
    const int b = blockIdx.y;
    const int g = blockIdx.x;
    const int t = threadIdx.x;
    const int lane = t & 63;
    const int kq = t >> 6;       // wave id = k quarter (2 nt-tiles of 16)
    const int lr = lane & 15;
    const int lg = lane >> 4;

    f32x4 acc[2][2];
#pragma unroll
    for (int pt = 0; pt < 2; ++pt)
#pragma unroll
        for (int nt = 0; nt < 2; ++nt) acc[pt][nt] = (f32x4)(0.f);

    for (int ch = 0; ch < 4; ++ch) {
        if (ch) __syncthreads();   // prior chunk's readers done before overwrite

        // ---- stage act tile [32 pos][128 i] ----
        if (VIEW <= 1) {
            const int cq = t & 7;        // pos quad: pos 4cq..+3
            const int rq = t >> 3;       // 0..31 -> rows 4rq..+3
            f32x4 v[4];
#pragma unroll
            for (int j = 0; j < 4; ++j) {
                int row = 4 * rq + j;
                size_t ga;
                if (VIEW == 0) {
                    ga = (size_t)(b * NC + ch * 128 + row) * SP + g * 32 + 4 * cq;
                } else {
                    int qh = row >> 6, w = row & 63;
                    ga = (size_t)(b * NC + 64 * (2 * ch + qh) + (g >> 1)) * SP +
                         w * 64 + (g & 1) * 32 + 4 * cq;
                }
                v[j] = *(const f32x4*)(x + ga);
            }
#pragma unroll
            for (int m = 0; m < 4; ++m) {
                int pos = 4 * cq + m;
                ushort4 u;
                u.x = f2bf(v[0][m]); u.y = f2bf(v[1][m]);
                u.z = f2bf(v[2][m]); u.w = f2bf(v[3][m]);
                *(ushort4*)((char*)actS + swzbyte(pos, 4 * rq)) = u;
            }
        } else {
            const int cb = 8 * (g >> 1) + 4 * (g & 1);
#pragma unroll
            for (int it = 0; it < 4; ++it) {
                int idx = it * 256 + t;      // 1024 float4
                int u = idx & 15;            // h quad
                int r = idx >> 4;            // 0..63
                int cl4 = r >> 4, jh = (r >> 1) & 7, qh = r & 1;
                size_t ga = (size_t)(b * NC + cb + cl4) * SP + (8 * (2 * ch + qh) + jh) * 64 + 4 * u;
                f32x4 v = *(const f32x4*)(x + ga);
                int pos = cl4 * 8 + jh;
                int iloc = 64 * qh + 4 * u;
                ushort4 uu;
                uu.x = f2bf(v.x); uu.y = f2bf(v.y); uu.z = f2bf(v.z); uu.w = f2bf(v.w);
                *(ushort4*)((char*)actS + swzbyte(pos, iloc)) = uu;
            }
        }
        __syncthreads();

        // ---- MFMA: A from LDS, B straight from wpre (1 KB coalesced) ----
#pragma unroll
        for (int kk = 0; kk < 4; ++kk) {
            const int ig = 4 * kk + lg;
            short8 a[2];
#pragma unroll
            for (int pt = 0; pt < 2; ++pt) {
                int prow = pt * 16 + lr;
                a[pt] = *(const short8*)((const char*)actS + swzbyte(prow, ig * 8));
            }
            short8 bf[2];
#pragma unroll
            for (int nt = 0; nt < 2; ++nt) {
                int idx16 = (ch * 4 + kk) * 8 + kq * 2 + nt;
                bf[nt] = *(const short8*)(wpre + (size_t)idx16 * 512 + lane * 8);
            }
#pragma unroll
            for (int pt = 0; pt < 2; ++pt)
#pragma unroll
                for (int nt = 0; nt < 2; ++nt)
                    acc[pt][nt] = __builtin_amdgcn_mfma_f32_16x16x32_bf16(a[pt], bf[nt], acc[pt][nt], 0, 0, 0);
        }
    }

    // ---- epilogue: relu(acc+bias), sum 32 pos; k-ranges are wave-exclusive
    // so red[] needs no atomics ----
#pragma unroll
    for (int nt = 0; nt < 2; ++nt) {
        int k = kq * 32 + nt * 16 + lr;
        float bv = bias[k];
        float s = 0.f;
#pragma unroll
        for (int pt = 0; pt < 2; ++pt)
#pragma unroll
            for (int rr = 0; rr < 4; ++rr)
                s += fmaxf(acc[pt][nt][rr] + bv, 0.f);
        s += __shfl_xor(s, 16);
        s += __shfl_xor(s, 32);
        if (lg == 0) red[k] = s;
    }
    __syncthreads();
    if (t < NK) atomicAdd(&Ssum[b * NK + t], red[t]);
}

// Merged conv launch: blockIdx.z selects the view (block-uniform branch).
// (256,6): reg cap 85; est. need ~76 (16-acc). r14 proved cap=32 is fatal;
// this is the TLP experiment at a safe cap.
__global__ __launch_bounds__(256, 6) void conv_all(
    const float* __restrict__ x,
    const unsigned short* __restrict__ wpre0, const unsigned short* __restrict__ wpre1,
    const float* __restrict__ bb, const float* __restrict__ ba,
    float* __restrict__ SY, float* __restrict__ SX1, float* __restrict__ SX2) {
    __shared__ __align__(16) unsigned short actS[32 * 128];   // 8 KB
    __shared__ float red[NK];
    const int view = blockIdx.z;
    if (view == 0)      conv_body<0>(x, wpre0, bb, SY,  actS, red);
    else if (view == 1) conv_body<1>(x, wpre1, ba, SX1, actS, red);
    else                conv_body<2>(x, wpre1, ba, SX2, actS, red);
}

// Per-(b,branch) MLP chain
__global__ __launch_bounds__(256) void chain_kernel(
    const float* __restrict__ Sy, const float* __restrict__ Sx1,
    const float* __restrict__ Sx2, const float* __restrict__ wd,
    const float* __restrict__ wc1, const float* __restrict__ bc1,
    const float* __restrict__ wc2, const float* __restrict__ bc2,
    float* __restrict__ sbr) {
    __shared__ float m[128];
    __shared__ float ap[512];
    __shared__ float z[128];
    const int b = blockIdx.x, br = blockIdx.y, t = threadIdx.x;
    const float* Sx = (br == 0) ? Sx1 : Sx2;
    const float inv = 1.0f / 4096.0f;

    if (t < 128) m[t] = (Sy[b * NK + t] + Sx[b * NK + t]) * inv;
    __syncthreads();
    for (int c = t; c < NC; c += 256) {
        float v = 0.f;
        for (int k = 0; k < NK; ++k) v += wd[c * NK + k] * m[k];
        ap[c] = v;
    }
    __syncthreads();
    if (t < 128) {
        float v = bc1[t];
        for (int c = 0; c < NC; ++c) v += wc1[t * NC + c] * ap[c];
        z[t] = fmaxf(v, 0.f);
    }
    __syncthreads();
    for (int c = t; c < NC; c += 256) {
        float v = bc2[c];
        for (int k = 0; k < NK; ++k) v += wc2[c * NK + k] * z[k];
        sbr[(br * NB + b) * NC + c] = 1.f / (1.f + expf(-v));
    }
}

// out[b,c,s] = x[b,c,s] + s1[b,c] + s2[b,c]  (streaming: nontemporal x/out)
__global__ __launch_bounds__(256) void final_add(
    const float* __restrict__ x, const float* __restrict__ sbr,
    float* __restrict__ out) {
    const int total4 = NB * NC * SP / 4;   // 8388608
    for (int i = blockIdx.x * 256 + threadIdx.x; i < total4; i += gridDim.x * 256) {
        int flat = i * 4;
        int bc = flat >> 12;
        int b = bc >> 9, c = bc & 511;
        float s = sbr[b * NC + c] + sbr[NB * NC + b * NC + c];
        f32x4 xv = __builtin_nontemporal_load((const f32x4*)x + i);
        f32x4 o = {xv.x + s, xv.y + s, xv.z + s, xv.w + s};
        __builtin_nontemporal_store(o, (f32x4*)out + i);
    }
}

extern "C" void kernel_launch(void* const* d_in, const int* in_sizes, int n_in,
                              void* d_out, int out_size, void* d_ws, size_t ws_size,
                              hipStream_t stream) {
    const float* x   = (const float*)d_in[0];
    const float* wa  = (const float*)d_in[1];
    const float* ba  = (const float*)d_in[2];
    const float* wb  = (const float*)d_in[3];
    const float* bb  = (const float*)d_in[4];
    const float* wd  = (const float*)d_in[5];
    const float* wc1 = (const float*)d_in[6];
    const float* bc1 = (const float*)d_in[7];
    const float* wc2 = (const float*)d_in[8];
    const float* bc2 = (const float*)d_in[9];
    float* out = (float*)d_out;

    float* ws  = (float*)d_ws;
    float* SY  = ws;
    float* SX1 = ws + 2048;
    float* SX2 = ws + 4096;
    float* sbr = ws + 6144;
    unsigned short* wpre0 = (unsigned short*)(ws + 22528);
    unsigned short* wpre1 = (unsigned short*)(ws + 55296);

    prep_weights<<<256, 256, 0, stream>>>(wa, wb, wpre0, wpre1, ws);
    conv_all<<<dim3(128, NB, 3), 256, 0, stream>>>(x, wpre0, wpre1, bb, ba, SY, SX1, SX2);
    chain_kernel<<<dim3(NB, 2), 256, 0, stream>>>(SY, SX1, SX2, wd, wc1, bc1, wc2, bc2, sbr);
    final_add<<<2048, 256, 0, stream>>>(x, sbr, out);
}

// Round 18
// 139.438 us; speedup vs baseline: 1.0476x; 1.0476x over previous
//
#include <hip/hip_runtime.h>
#include <math.h>

#define NB 16
#define NC 512
#define NK 128
#define SP 4096   // 64*64 spatial positions

typedef __attribute__((ext_vector_type(8))) short short8;
typedef __attribute__((ext_vector_type(4))) float f32x4;

__device__ inline unsigned short f2bf(float f) {
    unsigned int u = __builtin_bit_cast(unsigned int, f);
    u += 0x7fffu + ((u >> 16) & 1u);   // RNE
    return (unsigned short)(u >> 16);
}

// LDS act layout: byte(pos, iloc) = pos*256 + (G<<4) + (iloc&7)*2,
//   G = (iloc>>3) ^ (pos&7) ^ ((pos>>3)&7)
__device__ __forceinline__ int swzbyte(int pos, int iloc) {
    return pos * 256 + ((((iloc >> 3) ^ (pos & 7) ^ ((pos >> 3) & 7)) & 15) << 4) + (iloc & 7) * 2;
}

// ---------------------------------------------------------------------------
// ws layout (float offsets):
//   [0..2047] SY  [2048..4095] SX1  [4096..6143] SX2
//   [6144..22527]  sbr (2 br * 16 b * 512 c)
//   [22528..55295] wpre0 : wb pre-swizzled to per-wave B-frag order (65536 u16)
//   [55296..88063] wpre1 : wa (col-permuted) same order             (65536 u16)
//
// wpre element order: o = idx16*512 + lane*8 + el, where
//   idx16 = (ch*4 + kk)*8 + t8   (t8 = global 16-k tile = kq*2+nt)
//   k = t8*16 + (lane&15);  i = ch*128 + kk*32 + (lane>>4)*8 + el
// For wpre1 the logical column i' maps to wa column 8*(i'&63) + (i'>>6).
// ---------------------------------------------------------------------------

__global__ __launch_bounds__(256) void prep_weights(
    const float* __restrict__ wa, const float* __restrict__ wb,
    unsigned short* __restrict__ w0, unsigned short* __restrict__ w1,
    float* __restrict__ zbase) {
    int o = blockIdx.x * 256 + threadIdx.x;   // 0..65535
    if (o < 6144) zbase[o] = 0.f;             // zero SY/SX1/SX2 (replaces memset)
    int idx16 = o >> 9;
    int lane = (o >> 3) & 63;
    int el = o & 7;
    int t8 = idx16 & 7;
    int kk = (idx16 >> 3) & 3;
    int ch = idx16 >> 5;
    int k = t8 * 16 + (lane & 15);
    int i = ch * 128 + kk * 32 + (lane >> 4) * 8 + el;
    w0[o] = f2bf(wb[k * 512 + i]);
    int col1 = 8 * (i & 63) + (i >> 6);
    w1[o] = f2bf(wa[k * 512 + col1]);
}

// ---------------------------------------------------------------------------
// Conv+mean body, verified fragment math (r13/r16 base). Wave split changed:
// 4 waves = 4 kq (k-quarter, nt=2 tiles of 16); each wave covers ALL 64 pos
// (pt=4). B-frags load once per block (no inter-wave redundancy): weight
// VMEM bytes/block halved vs r13/r16. acc[4][2] = 32 regs (same footprint).
// VIEW 0: i = c = ch*128+iloc;            act elem = x[b, c, g, h=pos]
// VIEW 1: i'= 128ch+iloc (qh=iloc>>6,w=iloc&63): x[b, 64*(2ch+qh)+g, w, h=pos]
// VIEW 2: i'= 128ch+64qh+(h); pos=cl*8+jh:       x[b, 8g+cl, 8*(2ch+qh)+jh, h]
// ---------------------------------------------------------------------------
template <int VIEW>
__device__ __forceinline__ void conv_body(
    const float* __restrict__ x, const unsigned short* __restrict__ wpre,
    const float* __restrict__ bias, float* __restrict__ Ssum,
    unsigned short* actS, float* red) {
    const int b = blockIdx.y;
    const int g = blockIdx.x;
    const int t = threadIdx.x;
    const int lane = t & 63;
    const int kq = t >> 6;       // wave id = k quarter (2 nt-tiles of 16)
    const int lr = lane & 15;
    const int lg = lane >> 4;

    f32x4 acc[4][2];
#pragma unroll
    for (int pt = 0; pt < 4; ++pt)
#pragma unroll
        for (int nt = 0; nt < 2; ++nt) acc[pt][nt] = (f32x4)(0.f);

    for (int ch = 0; ch < 4; ++ch) {
        if (ch) __syncthreads();   // prior chunk's readers done before overwrite

        // ---- stage act tile [64 pos][128 i]: 8 loads up-front, then writes ----
        if (VIEW <= 1) {
            const int cq = t & 15;           // col quad -> pos 4cq..+3
            f32x4 v[8];
#pragma unroll
            for (int grp = 0; grp < 2; ++grp) {
                int rq = grp * 16 + (t >> 4);    // rows 4rq..+3
#pragma unroll
                for (int j = 0; j < 4; ++j) {
                    int row = 4 * rq + j;
                    size_t ga;
                    if (VIEW == 0) {
                        ga = (size_t)(b * NC + ch * 128 + row) * SP + g * 64 + 4 * cq;
                    } else {
                        int qh = row >> 6, w = row & 63;
                        ga = (size_t)(b * NC + 64 * (2 * ch + qh) + g) * SP + w * 64 + 4 * cq;
                    }
                    v[grp * 4 + j] = *(const f32x4*)(x + ga);
                }
            }
#pragma unroll
            for (int grp = 0; grp < 2; ++grp) {
                int rq = grp * 16 + (t >> 4);
#pragma unroll
                for (int m = 0; m < 4; ++m) {
                    int pos = 4 * cq + m;
                    ushort4 u;
                    u.x = f2bf(v[grp * 4 + 0][m]); u.y = f2bf(v[grp * 4 + 1][m]);
                    u.z = f2bf(v[grp * 4 + 2][m]); u.w = f2bf(v[grp * 4 + 3][m]);
                    *(ushort4*)((char*)actS + swzbyte(pos, 4 * rq)) = u;
                }
            }
        } else {
            const int u = t & 15;            // h quad
            f32x4 v[8];
#pragma unroll
            for (int it = 0; it < 8; ++it) {
                int r = it * 16 + (t >> 4);  // 0..127
                int cl = r >> 4, jh = (r >> 1) & 7, qh = r & 1;
                size_t ga = (size_t)(b * NC + 8 * g + cl) * SP + (8 * (2 * ch + qh) + jh) * 64 + 4 * u;
                v[it] = *(const f32x4*)(x + ga);
            }
#pragma unroll
            for (int it = 0; it < 8; ++it) {
                int r = it * 16 + (t >> 4);
                int cl = r >> 4, jh = (r >> 1) & 7, qh = r & 1;
                int pos = cl * 8 + jh;
                int iloc = 64 * qh + 4 * u;
                ushort4 uu;
                uu.x = f2bf(v[it].x); uu.y = f2bf(v[it].y);
                uu.z = f2bf(v[it].z); uu.w = f2bf(v[it].w);
                *(ushort4*)((char*)actS + swzbyte(pos, iloc)) = uu;
            }
        }
        __syncthreads();

        // ---- MFMA: A from LDS (4 pos-tiles), B from wpre (2 loads/kk) ----
#pragma unroll
        for (int kk = 0; kk < 4; ++kk) {
            const int ig = 4 * kk + lg;
            short8 bf[2];
#pragma unroll
            for (int nt = 0; nt < 2; ++nt) {
                int idx16 = (ch * 4 + kk) * 8 + kq * 2 + nt;
                bf[nt] = *(const short8*)(wpre + (size_t)idx16 * 512 + lane * 8);
            }
#pragma unroll
            for (int pt = 0; pt < 4; ++pt) {
                int prow = pt * 16 + lr;
                short8 a = *(const short8*)((const char*)actS + swzbyte(prow, ig * 8));
#pragma unroll
                for (int nt = 0; nt < 2; ++nt)
                    acc[pt][nt] = __builtin_amdgcn_mfma_f32_16x16x32_bf16(a, bf[nt], acc[pt][nt], 0, 0, 0);
            }
        }
    }

    // ---- epilogue: relu(acc+bias), sum all 64 pos; k-ranges wave-exclusive
    // so red[] needs no atomics ----
#pragma unroll
    for (int nt = 0; nt < 2; ++nt) {
        int k = kq * 32 + nt * 16 + lr;
        float bv = bias[k];
        float s = 0.f;
#pragma unroll
        for (int pt = 0; pt < 4; ++pt)
#pragma unroll
            for (int rr = 0; rr < 4; ++rr)
                s += fmaxf(acc[pt][nt][rr] + bv, 0.f);
        s += __shfl_xor(s, 16);
        s += __shfl_xor(s, 32);
        if (lg == 0) red[k] = s;
    }
    __syncthreads();
    if (t < NK) atomicAdd(&Ssum[b * NK + t], red[t]);
}

// Merged conv launch: blockIdx.z selects the view (block-uniform branch).
// (256,4): r14 showed tighter bounds force spills.
__global__ __launch_bounds__(256, 4) void conv_all(
    const float* __restrict__ x,
    const unsigned short* __restrict__ wpre0, const unsigned short* __restrict__ wpre1,
    const float* __restrict__ bb, const float* __restrict__ ba,
    float* __restrict__ SY, float* __restrict__ SX1, float* __restrict__ SX2) {
    __shared__ __align__(16) unsigned short actS[64 * 128];   // 16 KB
    __shared__ float red[NK];
    const int view = blockIdx.z;
    if (view == 0)      conv_body<0>(x, wpre0, bb, SY,  actS, red);
    else if (view == 1) conv_body<1>(x, wpre1, ba, SX1, actS, red);
    else                conv_body<2>(x, wpre1, ba, SX2, actS, red);
}

// Per-(b,branch) MLP chain
__global__ __launch_bounds__(256) void chain_kernel(
    const float* __restrict__ Sy, const float* __restrict__ Sx1,
    const float* __restrict__ Sx2, const float* __restrict__ wd,
    const float* __restrict__ wc1, const float* __restrict__ bc1,
    const float* __restrict__ wc2, const float* __restrict__ bc2,
    float* __restrict__ sbr) {
    __shared__ float m[128];
    __shared__ float ap[512];
    __shared__ float z[128];
    const int b = blockIdx.x, br = blockIdx.y, t = threadIdx.x;
    const float* Sx = (br == 0) ? Sx1 : Sx2;
    const float inv = 1.0f / 4096.0f;

    if (t < 128) m[t] = (Sy[b * NK + t] + Sx[b * NK + t]) * inv;
    __syncthreads();
    for (int c = t; c < NC; c += 256) {
        float v = 0.f;
        for (int k = 0; k < NK; ++k) v += wd[c * NK + k] * m[k];
        ap[c] = v;
    }
    __syncthreads();
    if (t < 128) {
        float v = bc1[t];
        for (int c = 0; c < NC; ++c) v += wc1[t * NC + c] * ap[c];
        z[t] = fmaxf(v, 0.f);
    }
    __syncthreads();
    for (int c = t; c < NC; c += 256) {
        float v = bc2[c];
        for (int k = 0; k < NK; ++k) v += wc2[c * NK + k] * z[k];
        sbr[(br * NB + b) * NC + c] = 1.f / (1.f + expf(-v));
    }
}

// out[b,c,s] = x[b,c,s] + s1[b,c] + s2[b,c]  (streaming: nontemporal x/out)
__global__ __launch_bounds__(256) void final_add(
    const float* __restrict__ x, const float* __restrict__ sbr,
    float* __restrict__ out) {
    const int total4 = NB * NC * SP / 4;   // 8388608
    for (int i = blockIdx.x * 256 + threadIdx.x; i < total4; i += gridDim.x * 256) {
        int flat = i * 4;
        int bc = flat >> 12;
        int b = bc >> 9, c = bc & 511;
        float s = sbr[b * NC + c] + sbr[NB * NC + b * NC + c];
        f32x4 xv = __builtin_nontemporal_load((const f32x4*)x + i);
        f32x4 o = {xv.x + s, xv.y + s, xv.z + s, xv.w + s};
        __builtin_nontemporal_store(o, (f32x4*)out + i);
    }
}

extern "C" void kernel_launch(void* const* d_in, const int* in_sizes, int n_in,
                              void* d_out, int out_size, void* d_ws, size_t ws_size,
                              hipStream_t stream) {
    const float* x   = (const float*)d_in[0];
    const float* wa  = (const float*)d_in[1];
    const float* ba  = (const float*)d_in[2];
    const float* wb  = (const float*)d_in[3];
    const float* bb  = (const float*)d_in[4];
    const float* wd  = (const float*)d_in[5];
    const float* wc1 = (const float*)d_in[6];
    const float* bc1 = (const float*)d_in[7];
    const float* wc2 = (const float*)d_in[8];
    const float* bc2 = (const float*)d_in[9];
    float* out = (float*)d_out;

    float* ws  = (float*)d_ws;
    float* SY  = ws;
    float* SX1 = ws + 2048;
    float* SX2 = ws + 4096;
    float* sbr = ws + 6144;
    unsigned short* wpre0 = (unsigned short*)(ws + 22528);
    unsigned short* wpre1 = (unsigned short*)(ws + 55296);

    prep_weights<<<256, 256, 0, stream>>>(wa, wb, wpre0, wpre1, ws);
    conv_all<<<dim3(64, NB, 3), 256, 0, stream>>>(x, wpre0, wpre1, bb, ba, SY, SX1, SX2);
    chain_kernel<<<dim3(NB, 2), 256, 0, stream>>>(SY, SX1, SX2, wd, wc1, bc1, wc2, bc2, sbr);
    final_add<<<2048, 256, 0, stream>>>(x, sbr, out);
}

// Round 19
// 136.408 us; speedup vs baseline: 1.0708x; 1.0222x over previous
//
#include <hip/hip_runtime.h>
#include <math.h>

#define NB 16
#define NC 512
#define NK 128
#define SP 4096   // 64*64 spatial positions

typedef __attribute__((ext_vector_type(8))) short short8;
typedef __attribute__((ext_vector_type(4))) float f32x4;

__device__ inline unsigned short f2bf(float f) {
    unsigned int u = __builtin_bit_cast(unsigned int, f);
    u += 0x7fffu + ((u >> 16) & 1u);   // RNE
    return (unsigned short)(u >> 16);
}

// LDS act layout: byte(pos, iloc) = pos*256 + (G<<4) + (iloc&7)*2,
//   G = (iloc>>3) ^ (pos&7) ^ ((pos>>3)&7)
__device__ __forceinline__ int swzbyte(int pos, int iloc) {
    return pos * 256 + ((((iloc >> 3) ^ (pos & 7) ^ ((pos >> 3) & 7)) & 15) << 4) + (iloc & 7) * 2;
}

// ---------------------------------------------------------------------------
// ws layout (float offsets):
//   [0..2047] SY  [2048..4095] SX1  [4096..6143] SX2
//   [6144..22527]  sbr (2 br * 16 b * 512 c)
//   [22528..55295] wpre0 : wb pre-swizzled to per-wave B-frag order (65536 u16)
//   [55296..88063] wpre1 : wa (col-permuted) same order             (65536 u16)
//
// wpre element order: o = idx16*512 + lane*8 + el, where
//   idx16 = (ch*4 + kk)*8 + t8   (t8 = global 16-k tile = kq*2+nt)
//   k = t8*16 + (lane&15);  i = ch*128 + kk*32 + (lane>>4)*8 + el
// For wpre1 the logical column i' maps to wa column 8*(i'&63) + (i'>>6).
// ---------------------------------------------------------------------------

__global__ __launch_bounds__(256) void prep_weights(
    const float* __restrict__ wa, const float* __restrict__ wb,
    unsigned short* __restrict__ w0, unsigned short* __restrict__ w1,
    float* __restrict__ zbase) {
    int o = blockIdx.x * 256 + threadIdx.x;   // 0..65535
    if (o < 6144) zbase[o] = 0.f;             // zero SY/SX1/SX2 (replaces memset)
    int idx16 = o >> 9;
    int lane = (o >> 3) & 63;
    int el = o & 7;
    int t8 = idx16 & 7;
    int kk = (idx16 >> 3) & 3;
    int ch = idx16 >> 5;
    int k = t8 * 16 + (lane & 15);
    int i = ch * 128 + kk * 32 + (lane >> 4) * 8 + el;
    w0[o] = f2bf(wb[k * 512 + i]);
    int col1 = 8 * (i & 63) + (i >> 6);
    w1[o] = f2bf(wa[k * 512 + col1]);
}

// ---------------------------------------------------------------------------
// Conv+mean body, verified fragment math (r18 base, byte-identical compute).
// 4 waves = 4 kq (k-quarter, nt=2 tiles of 16); each wave covers ALL 64 pos.
// VIEW 0: i = c = ch*128+iloc;            act elem = x[b, c, g, h=pos]
// VIEW 1: i'= 128ch+iloc (qh=iloc>>6,w=iloc&63): x[b, 64*(2ch+qh)+g, w, h=pos]
// VIEW 2: i'= 128ch+64qh+(h); pos=cl*8+jh:       x[b, 8g+cl, 8*(2ch+qh)+jh, h]
// ---------------------------------------------------------------------------
template <int VIEW>
__device__ __forceinline__ void conv_body(
    int b, int g,
    const float* __restrict__ x, const unsigned short* __restrict__ wpre,
    const float* __restrict__ bias, float* __restrict__ Ssum,
    unsigned short* actS, float* red) {
    const int t = threadIdx.x;
    const int lane = t & 63;
    const int kq = t >> 6;       // wave id = k quarter (2 nt-tiles of 16)
    const int lr = lane & 15;
    const int lg = lane >> 4;

    f32x4 acc[4][2];
#pragma unroll
    for (int pt = 0; pt < 4; ++pt)
#pragma unroll
        for (int nt = 0; nt < 2; ++nt) acc[pt][nt] = (f32x4)(0.f);

    for (int ch = 0; ch < 4; ++ch) {
        if (ch) __syncthreads();   // prior chunk's readers done before overwrite

        // ---- stage act tile [64 pos][128 i]: 8 loads up-front, then writes ----
        if (VIEW <= 1) {
            const int cq = t & 15;           // col quad -> pos 4cq..+3
            f32x4 v[8];
#pragma unroll
            for (int grp = 0; grp < 2; ++grp) {
                int rq = grp * 16 + (t >> 4);    // rows 4rq..+3
#pragma unroll
                for (int j = 0; j < 4; ++j) {
                    int row = 4 * rq + j;
                    size_t ga;
                    if (VIEW == 0) {
                        ga = (size_t)(b * NC + ch * 128 + row) * SP + g * 64 + 4 * cq;
                    } else {
                        int qh = row >> 6, w = row & 63;
                        ga = (size_t)(b * NC + 64 * (2 * ch + qh) + g) * SP + w * 64 + 4 * cq;
                    }
                    v[grp * 4 + j] = *(const f32x4*)(x + ga);
                }
            }
#pragma unroll
            for (int grp = 0; grp < 2; ++grp) {
                int rq = grp * 16 + (t >> 4);
#pragma unroll
                for (int m = 0; m < 4; ++m) {
                    int pos = 4 * cq + m;
                    ushort4 u;
                    u.x = f2bf(v[grp * 4 + 0][m]); u.y = f2bf(v[grp * 4 + 1][m]);
                    u.z = f2bf(v[grp * 4 + 2][m]); u.w = f2bf(v[grp * 4 + 3][m]);
                    *(ushort4*)((char*)actS + swzbyte(pos, 4 * rq)) = u;
                }
            }
        } else {
            const int u = t & 15;            // h quad
            f32x4 v[8];
#pragma unroll
            for (int it = 0; it < 8; ++it) {
                int r = it * 16 + (t >> 4);  // 0..127
                int cl = r >> 4, jh = (r >> 1) & 7, qh = r & 1;
                size_t ga = (size_t)(b * NC + 8 * g + cl) * SP + (8 * (2 * ch + qh) + jh) * 64 + 4 * u;
                v[it] = *(const f32x4*)(x + ga);
            }
#pragma unroll
            for (int it = 0; it < 8; ++it) {
                int r = it * 16 + (t >> 4);
                int cl = r >> 4, jh = (r >> 1) & 7, qh = r & 1;
                int pos = cl * 8 + jh;
                int iloc = 64 * qh + 4 * u;
                ushort4 uu;
                uu.x = f2bf(v[it].x); uu.y = f2bf(v[it].y);
                uu.z = f2bf(v[it].z); uu.w = f2bf(v[it].w);
                *(ushort4*)((char*)actS + swzbyte(pos, iloc)) = uu;
            }
        }
        __syncthreads();

        // ---- MFMA: A from LDS (4 pos-tiles), B from wpre (2 loads/kk) ----
#pragma unroll
        for (int kk = 0; kk < 4; ++kk) {
            const int ig = 4 * kk + lg;
            short8 bf[2];
#pragma unroll
            for (int nt = 0; nt < 2; ++nt) {
                int idx16 = (ch * 4 + kk) * 8 + kq * 2 + nt;
                bf[nt] = *(const short8*)(wpre + (size_t)idx16 * 512 + lane * 8);
            }
#pragma unroll
            for (int pt = 0; pt < 4; ++pt) {
                int prow = pt * 16 + lr;
                short8 a = *(const short8*)((const char*)actS + swzbyte(prow, ig * 8));
#pragma unroll
                for (int nt = 0; nt < 2; ++nt)
                    acc[pt][nt] = __builtin_amdgcn_mfma_f32_16x16x32_bf16(a, bf[nt], acc[pt][nt], 0, 0, 0);
            }
        }
    }

    // ---- epilogue: relu(acc+bias), sum all 64 pos; k-ranges wave-exclusive
    // so red[] needs no atomics ----
#pragma unroll
    for (int nt = 0; nt < 2; ++nt) {
        int k = kq * 32 + nt * 16 + lr;
        float bv = bias[k];
        float s = 0.f;
#pragma unroll
        for (int pt = 0; pt < 4; ++pt)
#pragma unroll
            for (int rr = 0; rr < 4; ++rr)
                s += fmaxf(acc[pt][nt][rr] + bv, 0.f);
        s += __shfl_xor(s, 16);
        s += __shfl_xor(s, 32);
        if (lg == 0) red[k] = s;
    }
    __syncthreads();
    if (t < NK) atomicAdd(&Ssum[b * NK + t], red[t]);
}

// Merged conv launch, 1-D grid with b SLOWEST: bid = b*192 + view*64 + g.
// The 192 blocks sharing x[b] (8.4 MB) are dispatch-adjacent -> ~4 slabs
// (~34 MB) co-resident in the 256 MB L3 -> each x byte fetched ~once.
__global__ __launch_bounds__(256, 4) void conv_all(
    const float* __restrict__ x,
    const unsigned short* __restrict__ wpre0, const unsigned short* __restrict__ wpre1,
    const float* __restrict__ bb, const float* __restrict__ ba,
    float* __restrict__ SY, float* __restrict__ SX1, float* __restrict__ SX2) {
    __shared__ __align__(16) unsigned short actS[64 * 128];   // 16 KB
    __shared__ float red[NK];
    const int bid = blockIdx.x;
    const int b = bid / 192;
    const int rem = bid - b * 192;
    const int view = rem >> 6;
    const int g = rem & 63;
    if (view == 0)      conv_body<0>(b, g, x, wpre0, bb, SY,  actS, red);
    else if (view == 1) conv_body<1>(b, g, x, wpre1, ba, SX1, actS, red);
    else                conv_body<2>(b, g, x, wpre1, ba, SX2, actS, red);
}

// Per-(b,branch) MLP chain
__global__ __launch_bounds__(256) void chain_kernel(
    const float* __restrict__ Sy, const float* __restrict__ Sx1,
    const float* __restrict__ Sx2, const float* __restrict__ wd,
    const float* __restrict__ wc1, const float* __restrict__ bc1,
    const float* __restrict__ wc2, const float* __restrict__ bc2,
    float* __restrict__ sbr) {
    __shared__ float m[128];
    __shared__ float ap[512];
    __shared__ float z[128];
    const int b = blockIdx.x, br = blockIdx.y, t = threadIdx.x;
    const float* Sx = (br == 0) ? Sx1 : Sx2;
    const float inv = 1.0f / 4096.0f;

    if (t < 128) m[t] = (Sy[b * NK + t] + Sx[b * NK + t]) * inv;
    __syncthreads();
    for (int c = t; c < NC; c += 256) {
        float v = 0.f;
        for (int k = 0; k < NK; ++k) v += wd[c * NK + k] * m[k];
        ap[c] = v;
    }
    __syncthreads();
    if (t < 128) {
        float v = bc1[t];
        for (int c = 0; c < NC; ++c) v += wc1[t * NC + c] * ap[c];
        z[t] = fmaxf(v, 0.f);
    }
    __syncthreads();
    for (int c = t; c < NC; c += 256) {
        float v = bc2[c];
        for (int k = 0; k < NK; ++k) v += wc2[c * NK + k] * z[k];
        sbr[(br * NB + b) * NC + c] = 1.f / (1.f + expf(-v));
    }
}

// out[b,c,s] = x[b,c,s] + s1[b,c] + s2[b,c]  (streaming: nontemporal x/out)
__global__ __launch_bounds__(256) void final_add(
    const float* __restrict__ x, const float* __restrict__ sbr,
    float* __restrict__ out) {
    const int total4 = NB * NC * SP / 4;   // 8388608
    for (int i = blockIdx.x * 256 + threadIdx.x; i < total4; i += gridDim.x * 256) {
        int flat = i * 4;
        int bc = flat >> 12;
        int b = bc >> 9, c = bc & 511;
        float s = sbr[b * NC + c] + sbr[NB * NC + b * NC + c];
        f32x4 xv = __builtin_nontemporal_load((const f32x4*)x + i);
        f32x4 o = {xv.x + s, xv.y + s, xv.z + s, xv.w + s};
        __builtin_nontemporal_store(o, (f32x4*)out + i);
    }
}

extern "C" void kernel_launch(void* const* d_in, const int* in_sizes, int n_in,
                              void* d_out, int out_size, void* d_ws, size_t ws_size,
                              hipStream_t stream) {
    const float* x   = (const float*)d_in[0];
    const float* wa  = (const float*)d_in[1];
    const float* ba  = (const float*)d_in[2];
    const float* wb  = (const float*)d_in[3];
    const float* bb  = (const float*)d_in[4];
    const float* wd  = (const float*)d_in[5];
    const float* wc1 = (const float*)d_in[6];
    const float* bc1 = (const float*)d_in[7];
    const float* wc2 = (const float*)d_in[8];
    const float* bc2 = (const float*)d_in[9];
    float* out = (float*)d_out;

    float* ws  = (float*)d_ws;
    float* SY  = ws;
    float* SX1 = ws + 2048;
    float* SX2 = ws + 4096;
    float* sbr = ws + 6144;
    unsigned short* wpre0 = (unsigned short*)(ws + 22528);
    unsigned short* wpre1 = (unsigned short*)(ws + 55296);

    prep_weights<<<256, 256, 0, stream>>>(wa, wb, wpre0, wpre1, ws);
    conv_all<<<dim3(192 * NB), 256, 0, stream>>>(x, wpre0, wpre1, bb, ba, SY, SX1, SX2);
    chain_kernel<<<dim3(NB, 2), 256, 0, stream>>>(SY, SX1, SX2, wd, wc1, bc1, wc2, bc2, sbr);
    final_add<<<2048, 256, 0, stream>>>(x, sbr, out);
}